// Round 4
// baseline (29.390 us; speedup 1.0000x reference)
//
#include <hip/hip_runtime.h>
#include <hip/hip_cooperative_groups.h>
#include <math.h>

namespace cg = cooperative_groups;

#define NB 32   // batch
#define CB 32   // capsule channels C
#define KC 10   // classes
#define PAD_LRT 260  // floats per lrT row (16B-aligned, 2-way free banking)
#define PAD_TP  168  // floats per Tp row

// sum over c of s_part[n][c][tid] followed by squash scaling for this (k,d); tid<160
__device__ __forceinline__ float squash_term(const float* __restrict__ sp, int n, int tid) {
    const float* p = sp + (size_t)n * (CB * 160) + tid;
    float t0 = 0.f, t1 = 0.f, t2 = 0.f, t3 = 0.f;
    #pragma unroll
    for (int cc = 0; cc < 32; cc += 4) {
        t0 += p[cc * 160];       t1 += p[(cc + 1) * 160];
        t2 += p[(cc + 2) * 160]; t3 += p[(cc + 3) * 160];
    }
    float ssum = (t0 + t1) + (t2 + t3);
    float sq = ssum * ssum;
    sq += __shfl_xor(sq, 1, 16);
    sq += __shfl_xor(sq, 2, 16);
    sq += __shfl_xor(sq, 4, 16);
    sq += __shfl_xor(sq, 8, 16);
    sq = fmaxf(sq, 1e-30f);
    return ssum * sq / ((1.f + sq) * sqrtf(sq));
}

// b = lr.E, softmax over k, write c row-major [k][m=tid]
__device__ __forceinline__ void softmax_c(const float lr[16], const float* __restrict__ E,
                                          float* __restrict__ c_out, int tid) {
    float b[KC];
    #pragma unroll
    for (int k = 0; k < KC; ++k) {
        const float4* e4 = (const float4*)(E + k * 16);
        float4 e0 = e4[0], e1 = e4[1], e2 = e4[2], e3 = e4[3];
        float acc = 0.f;
        acc = fmaf(lr[0], e0.x, acc);  acc = fmaf(lr[1], e0.y, acc);
        acc = fmaf(lr[2], e0.z, acc);  acc = fmaf(lr[3], e0.w, acc);
        acc = fmaf(lr[4], e1.x, acc);  acc = fmaf(lr[5], e1.y, acc);
        acc = fmaf(lr[6], e1.z, acc);  acc = fmaf(lr[7], e1.w, acc);
        acc = fmaf(lr[8], e2.x, acc);  acc = fmaf(lr[9], e2.y, acc);
        acc = fmaf(lr[10], e2.z, acc); acc = fmaf(lr[11], e2.w, acc);
        acc = fmaf(lr[12], e3.x, acc); acc = fmaf(lr[13], e3.y, acc);
        acc = fmaf(lr[14], e3.z, acc); acc = fmaf(lr[15], e3.w, acc);
        b[k] = acc;
    }
    float mx = b[0];
    #pragma unroll
    for (int k = 1; k < KC; ++k) mx = fmaxf(mx, b[k]);
    float sum = 0.f;
    #pragma unroll
    for (int k = 0; k < KC; ++k) { b[k] = __expf(b[k] - mx); sum += b[k]; }
    const float inv = 1.f / sum;
    #pragma unroll
    for (int k = 0; k < KC; ++k) c_out[k * 256 + tid] = b[k] * inv;
}

// Tp[mg][k*16+ij] = sum_{m in group mg} c[k][m] * lrT[ij][m]
__device__ __forceinline__ void tp_stage(const float* __restrict__ lrTp,
                                         const float* __restrict__ cl,
                                         float* __restrict__ Tp, int tid) {
    const int ij = tid & 15;
    const int mg = tid >> 4;
    const float4* lp = (const float4*)(lrTp + ij * PAD_LRT + mg * 16);
    float4 l0 = lp[0], l1 = lp[1], l2 = lp[2], l3 = lp[3];
    #pragma unroll
    for (int k = 0; k < KC; ++k) {
        const float4* cp = (const float4*)(cl + k * 256 + mg * 16);
        float4 c0 = cp[0], c1 = cp[1], c2 = cp[2], c3 = cp[3];
        float t = 0.f;
        t = fmaf(c0.x, l0.x, t); t = fmaf(c0.y, l0.y, t);
        t = fmaf(c0.z, l0.z, t); t = fmaf(c0.w, l0.w, t);
        t = fmaf(c1.x, l1.x, t); t = fmaf(c1.y, l1.y, t);
        t = fmaf(c1.z, l1.z, t); t = fmaf(c1.w, l1.w, t);
        t = fmaf(c2.x, l2.x, t); t = fmaf(c2.y, l2.y, t);
        t = fmaf(c2.z, l2.z, t); t = fmaf(c2.w, l2.w, t);
        t = fmaf(c3.x, l3.x, t); t = fmaf(c3.y, l3.y, t);
        t = fmaf(c3.z, l3.z, t); t = fmaf(c3.w, l3.w, t);
        Tp[mg * PAD_TP + k * 16 + ij] = t;
    }
}

__device__ __forceinline__ void t_reduce(const float* __restrict__ Tp,
                                         float* __restrict__ T, int tid) {
    if (tid < 160) {
        float t = 0.f;
        #pragma unroll
        for (int mg = 0; mg < 16; ++mg) t += Tp[mg * PAD_TP + tid];
        T[tid] = t;
    }
}

// s_part[k][i][le] = sum_j T[k][i*4+j] * w[k][j*4+le]
__device__ __forceinline__ void s_write(const float* __restrict__ T,
                                        const float* __restrict__ w,
                                        float* __restrict__ s_base, int tid) {
    if (tid < 160) {
        const int k = tid >> 4;
        const int i = (tid >> 2) & 3;
        const int le = tid & 3;
        float sv = 0.f;
        #pragma unroll
        for (int j = 0; j < 4; ++j)
            sv = fmaf(T[k * 16 + i * 4 + j], w[k * 16 + j * 4 + le], sv);
        s_base[tid] = sv;
    }
}

// ---------------- fused cooperative kernel: 512 blocks, 2 (n,c)-pairs per block
__global__ __launch_bounds__(256, 2) void caps_fused(
    const float* __restrict__ l,      // (N,C,16,16,16)
    const float* __restrict__ g,      // (N,10,16)
    const float* __restrict__ weight, // (C,10,4,4)
    float* __restrict__ s0,           // (N,C,160) partials
    float* __restrict__ s1,
    float* __restrict__ s2,
    float* __restrict__ out)          // [a(320) | v(5120)]
{
    __shared__ __align__(16) float w_lds[2][160];
    __shared__ __align__(16) float aeff_lds[160];
    __shared__ __align__(16) float E_lds[2][160];
    __shared__ __align__(16) float lrT[2][16 * PAD_LRT];
    __shared__ __align__(16) float c_lds[KC * 256];
    __shared__ __align__(16) float Tp[16 * PAD_TP];
    __shared__ __align__(16) float T_lds[2][160];

    cg::grid_group grid = cg::this_grid();
    const int tid = threadIdx.x;
    const int bid = blockIdx.x;
    const int n  = bid >> 4;        // 0..31
    const int c0 = bid & 15;        // pair channels: c0, c0+16
    const int c1 = c0 + 16;

    if (tid < 160) {
        w_lds[0][tid] = weight[c0 * 160 + tid];
        w_lds[1][tid] = weight[c1 * 160 + tid];
    }

    // load both pose matrices once; keep in registers + transposed LDS copies
    float lrA[16], lrB[16];
    {
        const float* la = l + (size_t)(n * CB + c0) * 4096 + tid;
        const float* lb = l + (size_t)(n * CB + c1) * 4096 + tid;
        #pragma unroll
        for (int ij = 0; ij < 16; ++ij) { lrA[ij] = la[ij * 256]; lrT[0][ij * PAD_LRT + tid] = lrA[ij]; }
        #pragma unroll
        for (int ij = 0; ij < 16; ++ij) { lrB[ij] = lb[ij * 256]; lrT[1][ij * PAD_LRT + tid] = lrB[ij]; }
    }

    #pragma unroll 1
    for (int it = 0; it < 3; ++it) {
        const float* sp0 = (it >= 1) ? s0 : nullptr;
        const float* sp1 = (it >= 2) ? s1 : nullptr;
        float* s_out = (it == 0) ? s0 : (it == 1) ? s1 : s2;

        // aeff depends on n only -> shared by both pairs
        if (tid < 160) {
            float a = g[n * 160 + tid];
            if (sp0) a += squash_term(sp0, n, tid);
            if (sp1) a += squash_term(sp1, n, tid);
            aeff_lds[tid] = a;
        }
        __syncthreads();                                   // S1

        if (tid < 160) {
            const int k = tid >> 4, i = (tid >> 2) & 3, j = tid & 3;
            const float* av = aeff_lds + k * 16;
            float e0 = 0.f, e1 = 0.f;
            #pragma unroll
            for (int ll = 0; ll < 4; ++ll) {
                const float a = av[i * 4 + ll];
                e0 = fmaf(a, w_lds[0][k * 16 + j * 4 + ll], e0);
                e1 = fmaf(a, w_lds[1][k * 16 + j * 4 + ll], e1);
            }
            E_lds[0][tid] = e0;
            E_lds[1][tid] = e1;
        }
        __syncthreads();                                   // S2

        softmax_c(lrA, E_lds[0], c_lds, tid);              // pair 0: b,softmax -> c
        __syncthreads();                                   // S3
        tp_stage(lrT[0], c_lds, Tp, tid);                  // pair 0 partial T
        __syncthreads();                                   // S4
        t_reduce(Tp, T_lds[0], tid);                       // pair 0 T
        softmax_c(lrB, E_lds[1], c_lds, tid);              // pair 1 c (c_lds free post-S4)
        __syncthreads();                                   // S5
        tp_stage(lrT[1], c_lds, Tp, tid);                  // pair 1 partial T
        s_write(T_lds[0], w_lds[0], s_out + (size_t)(n * CB + c0) * 160, tid);
        __syncthreads();                                   // S6
        t_reduce(Tp, T_lds[1], tid);                       // pair 1 T
        __syncthreads();                                   // S7
        s_write(T_lds[1], w_lds[1], s_out + (size_t)(n * CB + c1) * 160, tid);

        grid.sync();
    }

    // final: v = squash(sum_c s2), a = sigmoid(||v||); blocks 0..19 cover 5120 lanes
    if (bid < 20) {
        const int idx = bid * 256 + tid;
        const int nk = idx >> 4;
        const int d = idx & 15;
        const int nn = nk / 10;
        const int k = nk - nn * 10;
        const float* sp = s2 + (size_t)nn * (CB * 160) + k * 16 + d;
        float t0 = 0.f, t1 = 0.f, t2 = 0.f, t3 = 0.f;
        #pragma unroll
        for (int cc = 0; cc < 32; cc += 4) {
            t0 += sp[cc * 160];       t1 += sp[(cc + 1) * 160];
            t2 += sp[(cc + 2) * 160]; t3 += sp[(cc + 3) * 160];
        }
        float ssum = (t0 + t1) + (t2 + t3);
        float sq = ssum * ssum;
        sq += __shfl_xor(sq, 1, 16);
        sq += __shfl_xor(sq, 2, 16);
        sq += __shfl_xor(sq, 4, 16);
        sq += __shfl_xor(sq, 8, 16);
        sq = fmaxf(sq, 1e-30f);
        out[320 + nk * 16 + d] = ssum * sq / ((1.f + sq) * sqrtf(sq));
        if (d == 0) {
            const float nrm = sq / (1.f + sq);   // == ||v||
            out[nk] = 1.f / (1.f + __expf(-nrm));
        }
    }
}

// ---------------- fallback path (verified R2 kernels) ----------------
__global__ __launch_bounds__(256) void caps_main(
    const float* __restrict__ l, const float* __restrict__ g,
    const float* __restrict__ weight,
    const float* __restrict__ sp0, const float* __restrict__ sp1,
    float* __restrict__ s_out, int nv)
{
    __shared__ __align__(16) float w_lds[160];
    __shared__ __align__(16) float aeff_lds[160];
    __shared__ __align__(16) float E_lds[160];
    __shared__ __align__(16) float lrT1[16 * PAD_LRT];
    __shared__ __align__(16) float c_lds[KC * 256];
    __shared__ __align__(16) float Tp[16 * PAD_TP];
    __shared__ __align__(16) float T_lds[160];

    const int tid = threadIdx.x;
    const int n = blockIdx.x >> 5;
    const int c = blockIdx.x & 31;

    if (tid < 160) w_lds[tid] = weight[c * 160 + tid];

    float lr[16];
    const float* lbase = l + (size_t)(n * CB + c) * 4096 + tid;
    #pragma unroll
    for (int ij = 0; ij < 16; ++ij) lr[ij] = lbase[ij * 256];
    #pragma unroll
    for (int ij = 0; ij < 16; ++ij) lrT1[ij * PAD_LRT + tid] = lr[ij];

    if (tid < 160) {
        float a = g[n * 160 + tid];
        if (nv > 0) a += squash_term(sp0, n, tid);
        if (nv > 1) a += squash_term(sp1, n, tid);
        aeff_lds[tid] = a;
    }
    __syncthreads();

    if (tid < 160) {
        const int k = tid >> 4, i = (tid >> 2) & 3, j = tid & 3;
        const float* av = aeff_lds + k * 16;
        const float* wk = w_lds + k * 16;
        float e = 0.f;
        #pragma unroll
        for (int ll = 0; ll < 4; ++ll)
            e = fmaf(av[i * 4 + ll], wk[j * 4 + ll], e);
        E_lds[tid] = e;
    }
    __syncthreads();

    softmax_c(lr, E_lds, c_lds, tid);
    __syncthreads();
    tp_stage(lrT1, c_lds, Tp, tid);
    __syncthreads();
    t_reduce(Tp, T_lds, tid);
    __syncthreads();
    s_write(T_lds, w_lds, s_out + (size_t)blockIdx.x * 160, tid);
}

__global__ __launch_bounds__(256) void caps_final(
    const float* __restrict__ sp2, float* __restrict__ out)
{
    const int idx = blockIdx.x * 256 + threadIdx.x;
    const int nk = idx >> 4;
    const int d = idx & 15;
    const int n = nk / 10;
    const int k = nk - n * 10;
    const float* sp = sp2 + (size_t)n * (CB * 160) + k * 16 + d;
    float t0 = 0.f, t1 = 0.f, t2 = 0.f, t3 = 0.f;
    #pragma unroll
    for (int cc = 0; cc < 32; cc += 4) {
        t0 += sp[cc * 160];       t1 += sp[(cc + 1) * 160];
        t2 += sp[(cc + 2) * 160]; t3 += sp[(cc + 3) * 160];
    }
    float ssum = (t0 + t1) + (t2 + t3);
    float sq = ssum * ssum;
    sq += __shfl_xor(sq, 1, 16);
    sq += __shfl_xor(sq, 2, 16);
    sq += __shfl_xor(sq, 4, 16);
    sq += __shfl_xor(sq, 8, 16);
    sq = fmaxf(sq, 1e-30f);
    out[320 + nk * 16 + d] = ssum * sq / ((1.f + sq) * sqrtf(sq));
    if (d == 0) {
        const float nrm = sq / (1.f + sq);
        out[nk] = 1.f / (1.f + __expf(-nrm));
    }
}

extern "C" void kernel_launch(void* const* d_in, const int* in_sizes, int n_in,
                              void* d_out, int out_size, void* d_ws, size_t ws_size,
                              hipStream_t stream) {
    const float* l = (const float*)d_in[0];
    const float* g = (const float*)d_in[1];
    const float* w = (const float*)d_in[2];
    float* out = (float*)d_out;
    float* ws = (float*)d_ws;

    float* s0 = ws;                 // (N,C,160) = 163840 floats each
    float* s1 = ws + 163840;
    float* s2 = ws + 327680;

    // host-side co-residency pre-check (capture-transparent, deterministic)
    int perCU = 0, nCU = 0, dev = 0;
    (void)hipGetDevice(&dev);
    (void)hipDeviceGetAttribute(&nCU, hipDeviceAttributeMultiprocessorCount, dev);
    (void)hipOccupancyMaxActiveBlocksPerMultiprocessor(&perCU, caps_fused, 256, 0);

    hipError_t e = hipErrorUnknown;
    if ((long)perCU * (long)nCU >= 512) {
        void* args[] = { (void*)&l, (void*)&g, (void*)&w,
                         (void*)&s0, (void*)&s1, (void*)&s2, (void*)&out };
        e = hipLaunchCooperativeKernel((void*)caps_fused, dim3(512), dim3(256),
                                       args, 0, stream);
    }
    if (e != hipSuccess) {
        // verified 4-kernel fallback
        caps_main<<<dim3(NB * CB), dim3(256), 0, stream>>>(l, g, w, nullptr, nullptr, s0, 0);
        caps_main<<<dim3(NB * CB), dim3(256), 0, stream>>>(l, g, w, s0, nullptr, s1, 1);
        caps_main<<<dim3(NB * CB), dim3(256), 0, stream>>>(l, g, w, s0, s1, s2, 2);
        caps_final<<<dim3(20), dim3(256), 0, stream>>>(s2, out);
    }
}